// Round 12
// baseline (281.183 us; speedup 1.0000x reference)
//
#include <hip/hip_runtime.h>

typedef _Float16 f16;
typedef __attribute__((ext_vector_type(4))) _Float16 f16x4;
typedef __attribute__((ext_vector_type(8))) _Float16 f16x8;
typedef __attribute__((ext_vector_type(4))) float f32x4;

#define B_ 8192
#define D_ 784
#define H_ 1024
#define L_ 128
#define T_ 10
#define KP1 896          // Xp row stride (D padded)
#define MAXTILES (B_/128 + T_)   // 74 (128-row tile map)
#define PADROWS 256
#define BLDS 16384       // B LDS base
#define BSTR 136         // B LDS row stride (bytes): 64 f16 + 8B pad

// ctrl int indices
#define C_COUNT 0
#define C_CURS 16
#define C_OFFS 32
#define C_NTILES 49
#define C_TTASK 64
#define C_TROW 160

__global__ void k_init(int* ctrl) {
    if (threadIdx.x < 64) ctrl[threadIdx.x] = 0;
}

__global__ void k_count(const int* __restrict__ task, int* __restrict__ ctrl) {
    int b = blockIdx.x * 256 + threadIdx.x;
    if (b < B_) atomicAdd(&ctrl[C_COUNT + task[b]], 1);
}

__global__ void k_scan(int* ctrl) {
    if (threadIdx.x == 0 && blockIdx.x == 0) {
        int off = 0;
        ctrl[C_OFFS] = 0;
        for (int t = 0; t < T_; ++t) { off += ctrl[C_COUNT + t]; ctrl[C_OFFS + t + 1] = off; }
        int nt = 0;
        for (int t = 0; t < T_; ++t)
            for (int r = ctrl[C_OFFS + t]; r < ctrl[C_OFFS + t + 1]; r += 128) {
                ctrl[C_TTASK + nt] = t; ctrl[C_TROW + nt] = r; ++nt;
            }
        ctrl[C_NTILES] = nt;
    }
}

__global__ void k_scatter(const int* __restrict__ task, int* __restrict__ ctrl, int* __restrict__ perm) {
    int b = blockIdx.x * 256 + threadIdx.x;
    if (b >= B_) return;
    int t = task[b];
    int i = ctrl[C_OFFS + t] + atomicAdd(&ctrl[C_CURS + t], 1);
    perm[i] = b;
}

__global__ void k_gather_x(const float* __restrict__ x, const int* __restrict__ perm, f16* __restrict__ Xp) {
    int i = blockIdx.x;
    int r = perm[i];
    int c = threadIdx.x * 4;
    if (c >= KP1) return;
    f16x4 o = (f16x4){0, 0, 0, 0};
    if (c < D_) {
        float4 v = *(const float4*)(x + (long)r * D_ + c);
        o[0] = (f16)v.x; o[1] = (f16)v.y; o[2] = (f16)v.z; o[3] = (f16)v.w;
    }
    *(f16x4*)(Xp + (long)i * KP1 + c) = o;
}

// z = mu + exp(ls) * eps  (permuted rows)
__global__ void k_z(const float* __restrict__ mu, const float* __restrict__ ls,
                    const float* __restrict__ eps, const int* __restrict__ perm,
                    f16* __restrict__ Z) {
    long gid = (long)blockIdx.x * 256 + threadIdx.x;
    int i = (int)(gid >> 7), c = (int)(gid & 127);
    int r = perm[i];
    float m = mu[(long)r * L_ + c];
    float l = ls[(long)r * L_ + c];
    Z[(long)i * L_ + c] = (f16)(m + __expf(l) * eps[(long)r * L_ + c]);
}

// ---------------------------------------------------------------------------
// 128M x 64N GEMM with FUSED fp32->f16 weight conversion in B-staging.
// A: f16 [rows][lda] via global_load_lds (swizzled, as r11).
// B: fp32 natural [K][N]; each thread loads a 4kx4n block (coalesced),
//    converts + transposes in-register, ds_writes f16x4 into LDS [n][k]
//    (row stride 136B). Guards handle K/N padding -- no weight pre-pass.
// 4 waves (2Mx2N), per-wave 64x32 = acc[4][2] of 16x16x32 f16 MFMA.
// m97-style sync-sync loop; latency hiding via ~4 co-resident blocks/CU.
// ---------------------------------------------------------------------------
template <int EPI, bool GROUPED>
__global__ __launch_bounds__(256, 4)
void k_gemmE(const f16* __restrict__ A, int lda,
             const float* __restrict__ W, long wstride,
             const float* __restrict__ bias, int bstride,
             int NI, int Kreal, int Nreal, int ntn,
             f16* __restrict__ outF16, float* __restrict__ o0, float* __restrict__ o1,
             const int* __restrict__ ctrl, const int* __restrict__ perm) {
    __shared__ char lds[BLDS + 64 * BSTR];   // A 16KB + B 8.5KB
    int tid = threadIdx.x, lane = tid & 63;
    int wave = tid >> 6, wm = wave >> 1, wn = wave & 1;

    // bijective XCD swizzle (m204)
    int nwg = gridDim.x, orig = blockIdx.x;
    int qq = nwg >> 3, rr8 = nwg & 7, xcd = orig & 7, idx = orig >> 3;
    int wgid = (xcd < rr8 ? xcd * (qq + 1) : rr8 * (qq + 1) + (xcd - rr8) * qq) + idx;
    int tm = wgid / ntn, tn = wgid - tm * ntn;

    int t, row0, mrows;
    if (GROUPED) {
        if (tm >= ctrl[C_NTILES]) return;
        t = ctrl[C_TTASK + tm];
        row0 = ctrl[C_TROW + tm];
        mrows = min(128, ctrl[C_OFFS + t + 1] - row0);
    } else {
        t = 0; row0 = tm * 128; mrows = 128;
    }
    const float* Wt = W + (long)t * wstride;
    const float* bt = bias + (long)t * bstride;
    int n0 = tn * 64;

    // ---- A staging invariants (r11, verified) ----
    int rowc = tid >> 3;
    long srcElem = (long)rowc * lda + (((tid & 7) ^ (rowc & 7)) << 3);
    int dstOff = wave << 10;
    const f16* Abase = A + (long)row0 * lda + srcElem;
    int slot0 = ((lane >> 4) ^ (lane & 7)) << 4;
    const char* aptr = lds + (wm * 64 + (lane & 15)) * 128 + slot0;

    // ---- B staging invariants ----
    int bq = tid >> 4;            // k-quad 0..15
    int bs = tid & 15;            // n-quad 0..15
    int bn = n0 + 4 * bs;         // global n of this thread's 4 cols
    bool nok = (bn < Nreal);      // Nreal % 4 == 0 -> whole float4 in/out
    const float* Wb = Wt + bn;    // + k*Nreal
    char* bwr = lds + BLDS + (4 * bs) * BSTR + bq * 8;   // + j*BSTR

    // B fragment read base: two f16x4 at +0,+8
    const char* brd = lds + BLDS + (wn * 32 + (lane & 15)) * BSTR + ((lane >> 4) << 4);

    f32x4 acc[4][2];
#pragma unroll
    for (int i = 0; i < 4; ++i)
#pragma unroll
        for (int j = 0; j < 2; ++j) acc[i][j] = (f32x4){0.f, 0.f, 0.f, 0.f};

    float4 cur0, cur1, cur2, cur3;
    auto LOADB = [&](int kt, float4& v0, float4& v1, float4& v2, float4& v3) {
        int kb = kt * 64 + 4 * bq;
        float4 z = {0.f, 0.f, 0.f, 0.f};
        v0 = (nok && kb + 0 < Kreal) ? *(const float4*)(Wb + (long)(kb + 0) * Nreal) : z;
        v1 = (nok && kb + 1 < Kreal) ? *(const float4*)(Wb + (long)(kb + 1) * Nreal) : z;
        v2 = (nok && kb + 2 < Kreal) ? *(const float4*)(Wb + (long)(kb + 2) * Nreal) : z;
        v3 = (nok && kb + 3 < Kreal) ? *(const float4*)(Wb + (long)(kb + 3) * Nreal) : z;
    };

    LOADB(0, cur0, cur1, cur2, cur3);
    for (int kt = 0; kt < NI; ++kt) {
        // A stage (async to LDS)
        const f16* a = Abase + kt * 64;
#pragma unroll
        for (int c = 0; c < 4; ++c)
            __builtin_amdgcn_global_load_lds(
                (const __attribute__((address_space(1))) unsigned int*)(a + (long)c * 32 * lda),
                (__attribute__((address_space(3))) unsigned int*)(lds + c * 4096 + dstOff), 16, 0, 0);
        // prefetch next B tile (in flight until the barrier)
        float4 nxt0, nxt1, nxt2, nxt3;
        if (kt + 1 < NI) LOADB(kt + 1, nxt0, nxt1, nxt2, nxt3);
        // convert + transpose + LDS write current B tile
        {
            f16x4 c0 = {(f16)cur0.x, (f16)cur1.x, (f16)cur2.x, (f16)cur3.x};
            f16x4 c1 = {(f16)cur0.y, (f16)cur1.y, (f16)cur2.y, (f16)cur3.y};
            f16x4 c2 = {(f16)cur0.z, (f16)cur1.z, (f16)cur2.z, (f16)cur3.z};
            f16x4 c3 = {(f16)cur0.w, (f16)cur1.w, (f16)cur2.w, (f16)cur3.w};
            *(f16x4*)(bwr + 0 * BSTR) = c0;
            *(f16x4*)(bwr + 1 * BSTR) = c1;
            *(f16x4*)(bwr + 2 * BSTR) = c2;
            *(f16x4*)(bwr + 3 * BSTR) = c3;
        }
        __syncthreads();   // A landed, B writes visible

#pragma unroll
        for (int ks = 0; ks < 2; ++ks) {
            int xo = ((slot0 ^ (ks * 64)) - slot0);
            f16x8 af[4], bf[2];
#pragma unroll
            for (int mi = 0; mi < 4; ++mi)
                af[mi] = *(const f16x8*)(aptr + mi * 2048 + xo);
#pragma unroll
            for (int nj = 0; nj < 2; ++nj) {
                f16x4 lo = *(const f16x4*)(brd + nj * (16 * BSTR) + ks * 64);
                f16x4 hi = *(const f16x4*)(brd + nj * (16 * BSTR) + ks * 64 + 8);
                f16x8 b;
                b[0] = lo[0]; b[1] = lo[1]; b[2] = lo[2]; b[3] = lo[3];
                b[4] = hi[0]; b[5] = hi[1]; b[6] = hi[2]; b[7] = hi[3];
                bf[nj] = b;
            }
#pragma unroll
            for (int mi = 0; mi < 4; ++mi)
#pragma unroll
                for (int nj = 0; nj < 2; ++nj)
                    acc[mi][nj] = __builtin_amdgcn_mfma_f32_16x16x32_f16(af[mi], bf[nj], acc[mi][nj], 0, 0, 0);
        }
        __syncthreads();   // reads done before next iter's writes
        cur0 = nxt0; cur1 = nxt1; cur2 = nxt2; cur3 = nxt3;
    }

    // epilogue
    int cq = lane >> 4, cr = lane & 15;
#pragma unroll
    for (int mi = 0; mi < 4; ++mi) {
#pragma unroll
        for (int nj = 0; nj < 2; ++nj) {
#pragma unroll
            for (int reg = 0; reg < 4; ++reg) {
                int rl = wm * 64 + mi * 16 + cq * 4 + reg;
                if (rl >= mrows) continue;
                int gcol = n0 + wn * 32 + nj * 16 + cr;
                if (gcol >= Nreal) continue;
                float v = acc[mi][nj][reg] + bt[gcol];
                int grow = row0 + rl;
                if (EPI == 0) {
                    outF16[(long)grow * H_ + gcol] = (f16)(v > 0.f ? v : 0.f);
                } else if (EPI == 1) {
                    int r = perm[grow];
                    if (gcol < L_) o0[(long)r * L_ + gcol] = v;
                    else o1[(long)r * L_ + (gcol - L_)] = v;
                } else {
                    o0[(long)perm[grow] * D_ + gcol] = 1.f / (1.f + __expf(-v));
                }
            }
        }
    }
}

extern "C" void kernel_launch(void* const* d_in, const int* in_sizes, int n_in,
                              void* d_out, int out_size, void* d_ws, size_t ws_size,
                              hipStream_t stream) {
    const float* x   = (const float*)d_in[0];
    const float* eps = (const float*)d_in[1];
    const float* eW1 = (const float*)d_in[2];
    const float* eb1 = (const float*)d_in[3];
    const float* eW2 = (const float*)d_in[4];
    const float* eb2 = (const float*)d_in[5];
    const float* eW3 = (const float*)d_in[6];
    const float* eb3 = (const float*)d_in[7];
    const float* dW1 = (const float*)d_in[8];
    const float* db1 = (const float*)d_in[9];
    const float* dW2 = (const float*)d_in[10];
    const float* db2 = (const float*)d_in[11];
    const float* hW  = (const float*)d_in[12];
    const float* hb  = (const float*)d_in[13];
    const int* task  = (const int*)d_in[14];

    float* out = (float*)d_out;
    float* recon = out;
    float* mu = out + (size_t)B_ * D_;
    float* ls = mu + (size_t)B_ * L_;

    char* w = (char*)d_ws;
    size_t o = 0;
    auto alloc = [&](size_t bytes) -> char* {
        char* p = w + o;
        o = (o + bytes + 255) & ~(size_t)255;
        return p;
    };
    int* ctrl  = (int*)alloc(4096);
    int* perm  = (int*)alloc((size_t)B_ * 4);
    f16* Xp    = (f16*)alloc((size_t)(B_ + PADROWS) * KP1 * 2);
    f16* H1    = (f16*)alloc((size_t)(B_ + PADROWS) * H_ * 2);
    f16* H2    = (f16*)alloc((size_t)(B_ + PADROWS) * H_ * 2);
    f16* Z     = (f16*)alloc((size_t)(B_ + PADROWS) * L_ * 2);
    if (o > ws_size) return;

    k_init<<<1, 64, 0, stream>>>(ctrl);
    k_count<<<B_ / 256, 256, 0, stream>>>(task, ctrl);
    k_scan<<<1, 1, 0, stream>>>(ctrl);
    k_scatter<<<B_ / 256, 256, 0, stream>>>(task, ctrl, perm);
    k_gather_x<<<B_, 256, 0, stream>>>(x, perm, Xp);

    int gridG  = MAXTILES * 16;    // 1184 (grouped, 16 N-tiles of 64)
    int gridG3 = MAXTILES * 4;     // 296 (enc3, N=256)
    int gridD  = (B_ / 128) * 16;  // 1024 (dense)
    int gridH  = MAXTILES * 13;    // 962 (head, 13 N-tiles cover 784..832)

    // encoder layer 1: Xp(lda=896, K=784) @ eW1 -> relu -> H1
    k_gemmE<0, true><<<gridG, 256, 0, stream>>>(
        Xp, KP1, eW1, (long)D_ * H_, eb1, H_, 13, D_, H_, 16,
        H1, nullptr, nullptr, ctrl, perm);
    // encoder layer 2: H1 @ eW2 -> relu -> H2
    k_gemmE<0, true><<<gridG, 256, 0, stream>>>(
        H1, H_, eW2, (long)H_ * H_, eb2, H_, 16, H_, H_, 16,
        H2, nullptr, nullptr, ctrl, perm);
    // encoder layer 3: H2 @ eW3 -> mu/ls perm-scatter
    k_gemmE<1, true><<<gridG3, 256, 0, stream>>>(
        H2, H_, eW3, (long)H_ * 256, eb3, 256, 16, H_, 256, 4,
        nullptr, mu, ls, ctrl, perm);
    // z = mu + exp(ls)*eps
    k_z<<<(B_ * L_) / 256, 256, 0, stream>>>(mu, ls, eps, perm, Z);
    // decoder layer 1: Z(K=128) @ dW1 -> relu -> H1
    k_gemmE<0, false><<<gridD, 256, 0, stream>>>(
        Z, L_, dW1, 0, db1, 0, 2, L_, H_, 16,
        H1, nullptr, nullptr, ctrl, perm);
    // decoder layer 2: H1 @ dW2 -> relu -> H2
    k_gemmE<0, false><<<gridD, 256, 0, stream>>>(
        H1, H_, dW2, 0, db2, 0, 16, H_, H_, 16,
        H2, nullptr, nullptr, ctrl, perm);
    // head: H2 @ hW -> sigmoid -> recon (perm-scatter fp32)
    k_gemmE<2, true><<<gridH, 256, 0, stream>>>(
        H2, H_, hW, (long)H_ * D_, hb, D_, 16, H_, D_, 13,
        nullptr, recon, nullptr, ctrl, perm);
}

// Round 13
// 280.899 us; speedup vs baseline: 1.0010x; 1.0010x over previous
//
#include <hip/hip_runtime.h>

typedef _Float16 f16;
typedef __attribute__((ext_vector_type(4))) _Float16 f16x4;
typedef __attribute__((ext_vector_type(8))) _Float16 f16x8;
typedef __attribute__((ext_vector_type(4))) float f32x4;

#define B_ 8192
#define D_ 784
#define H_ 1024
#define L_ 128
#define T_ 10
#define KP1 896          // D padded to multiple of 64
#define NPH 896          // head N padded to 896
#define MAXTILES (B_/128 + T_)   // 74 (128-row tile map)
#define PADROWS 256

// ctrl int indices
#define C_COUNT 0
#define C_CURS 16
#define C_OFFS 32
#define C_NTILES 49
#define C_TTASK 64
#define C_TROW 160

__global__ void k_init(int* ctrl) {
    if (threadIdx.x < 64) ctrl[threadIdx.x] = 0;
}

__global__ void k_count(const int* __restrict__ task, int* __restrict__ ctrl) {
    int b = blockIdx.x * 256 + threadIdx.x;
    if (b < B_) atomicAdd(&ctrl[C_COUNT + task[b]], 1);
}

__global__ void k_scan(int* ctrl) {
    if (threadIdx.x == 0 && blockIdx.x == 0) {
        int off = 0;
        ctrl[C_OFFS] = 0;
        for (int t = 0; t < T_; ++t) { off += ctrl[C_COUNT + t]; ctrl[C_OFFS + t + 1] = off; }
        int nt = 0;
        for (int t = 0; t < T_; ++t)
            for (int r = ctrl[C_OFFS + t]; r < ctrl[C_OFFS + t + 1]; r += 128) {
                ctrl[C_TTASK + nt] = t; ctrl[C_TROW + nt] = r; ++nt;
            }
        ctrl[C_NTILES] = nt;
    }
}

__global__ void k_scatter(const int* __restrict__ task, int* __restrict__ ctrl, int* __restrict__ perm) {
    int b = blockIdx.x * 256 + threadIdx.x;
    if (b >= B_) return;
    int t = task[b];
    int i = ctrl[C_OFFS + t] + atomicAdd(&ctrl[C_CURS + t], 1);
    perm[i] = b;
}

__global__ void k_gather_x(const float* __restrict__ x, const int* __restrict__ perm, f16* __restrict__ Xp) {
    int i = blockIdx.x;
    int r = perm[i];
    int c = threadIdx.x * 4;
    if (c >= KP1) return;
    f16x4 o = (f16x4){0, 0, 0, 0};
    if (c < D_) {
        float4 v = *(const float4*)(x + (long)r * D_ + c);
        o[0] = (f16)v.x; o[1] = (f16)v.y; o[2] = (f16)v.z; o[3] = (f16)v.w;
    }
    *(f16x4*)(Xp + (long)i * KP1 + c) = o;
}

// ---------------------------------------------------------------------------
// Fused transpose-convert, 64K x 128N fp32 tiles (8 float4 loads in flight
// per thread -- 2x r11's depth; duty-cycle fix). tile[64][133]: 133 = 5 mod 32
// makes the transposed read 2-way bank-aliased (free, m136); write 4-way on
// 4 scalar stores (negligible).
// ---------------------------------------------------------------------------
struct ConvSeg { const float* src; f16* dst; int K, N, Kp, Np, ntx, nty, base; };
struct ConvArgs { ConvSeg s[6]; };

__global__ __launch_bounds__(256)
void k_convAll(ConvArgs args) {
    __shared__ float tile[64][133];
    int bid = blockIdx.x;
    int si = 0;
#pragma unroll
    for (int i = 1; i < 6; ++i) si = (bid >= args.s[i].base) ? i : si;
    ConvSeg sg = args.s[si];
    int rel = bid - sg.base;
    int perT = sg.ntx * sg.nty;
    int t = rel / perT; rel -= t * perT;
    int ty = rel / sg.ntx;            // n-tile (128 wide)
    int tx = rel - ty * sg.ntx;       // k-tile (64)
    int k0 = tx * 64, n0 = ty * 128;
    const float* s = sg.src + (long)t * sg.K * sg.N;
    f16* d = sg.dst + (long)t * sg.Np * sg.Kp;
    int tid = threadIdx.x;

    // read: 32 threads per k-row (float4 each), 8 rows per pass, 8 passes
    int rr = tid >> 5, cc = (tid & 31) * 4;
#pragma unroll
    for (int p = 0; p < 8; ++p) {
        int k = k0 + rr + p * 8;
        int gn = n0 + cc;
        float4 v = {0.f, 0.f, 0.f, 0.f};
        if (k < sg.K) {
            const float* sp = s + (long)k * sg.N + gn;
            if (gn + 3 < sg.N) v = *(const float4*)sp;
            else {
                if (gn + 0 < sg.N) v.x = sp[0];
                if (gn + 1 < sg.N) v.y = sp[1];
                if (gn + 2 < sg.N) v.z = sp[2];
                if (gn + 3 < sg.N) v.w = sp[3];
            }
        }
        tile[rr + p * 8][cc + 0] = v.x;
        tile[rr + p * 8][cc + 1] = v.y;
        tile[rr + p * 8][cc + 2] = v.z;
        tile[rr + p * 8][cc + 3] = v.w;
    }
    __syncthreads();
    // write: 8 threads per n-row (f16x8 each), 32 n-rows per pass, 4 passes
    int nr = tid >> 3, kk = (tid & 7) * 8;
#pragma unroll
    for (int p = 0; p < 4; ++p) {
        int n = n0 + nr + p * 32;
        f16x8 o;
#pragma unroll
        for (int u = 0; u < 8; ++u) o[u] = (f16)tile[kk + u][nr + p * 32];
        if (n < sg.Np) *(f16x8*)(d + (long)n * sg.Kp + k0 + kk) = o;
    }
}

// z = mu + exp(ls) * eps  (permuted rows)
__global__ void k_z(const float* __restrict__ mu, const float* __restrict__ ls,
                    const float* __restrict__ eps, const int* __restrict__ perm,
                    f16* __restrict__ Z) {
    long gid = (long)blockIdx.x * 256 + threadIdx.x;
    int i = (int)(gid >> 7), c = (int)(gid & 127);
    int r = perm[i];
    float m = mu[(long)r * L_ + c];
    float l = ls[(long)r * L_ + c];
    Z[(long)i * L_ + c] = (f16)(m + __expf(l) * eps[(long)r * L_ + c]);
}

// ---------------------------------------------------------------------------
// 128M x 64N GEMM, BK=64, SINGLE 24KB LDS buffer, 4 waves (2Mx2N),
// per-wave 64x32 = acc[4][2] of 16x16x32 f16 MFMA.  (r11, verified best)
// ---------------------------------------------------------------------------
template <int EPI, bool GROUPED>
__global__ __launch_bounds__(256, 4)
void k_gemmD(const f16* __restrict__ A,
             const f16* __restrict__ W, long wstride,
             const float* __restrict__ bias, int bstride,
             int K, int N, int ntn,
             f16* __restrict__ outF16, float* __restrict__ o0, float* __restrict__ o1,
             const int* __restrict__ ctrl, const int* __restrict__ perm) {
    __shared__ char lds[24576];   // A [128][64]f16 @0 (16KB), B [64][64] @16384 (8KB)
    int tid = threadIdx.x, lane = tid & 63;
    int wave = tid >> 6, wm = wave >> 1, wn = wave & 1;

    // bijective XCD swizzle (m204)
    int nwg = gridDim.x, orig = blockIdx.x;
    int qq = nwg >> 3, rr8 = nwg & 7, xcd = orig & 7, idx = orig >> 3;
    int wgid = (xcd < rr8 ? xcd * (qq + 1) : rr8 * (qq + 1) + (xcd - rr8) * qq) + idx;
    int tm = wgid / ntn, tn = wgid - tm * ntn;

    int t, row0, mrows;
    if (GROUPED) {
        if (tm >= ctrl[C_NTILES]) return;
        t = ctrl[C_TTASK + tm];
        row0 = ctrl[C_TROW + tm];
        mrows = min(128, ctrl[C_OFFS + t + 1] - row0);
    } else {
        t = 0; row0 = tm * 128; mrows = 128;
    }
    const f16* Wt = W + (long)t * wstride;
    const float* bt = bias + (long)t * bstride;
    int n0 = tn * 64;

    // staging: thread g covers (row g>>3 in a 32-row chunk, LDS slot g&7);
    // global 16B-chunk = (g&7) ^ (row&7)  (inverse swizzle).
    int rowc = tid >> 3;   // 0..31
    long srcElem = (long)rowc * K + (((tid & 7) ^ (rowc & 7)) << 3);
    int dstOff = wave << 10;   // wave-uniform; HW adds lane*16
    const f16* Abase = A + (long)row0 * K + srcElem;
    const f16* Bbase = Wt + (long)n0 * K + srcElem;

    f32x4 acc[4][2];
#pragma unroll
    for (int i = 0; i < 4; ++i)
#pragma unroll
        for (int j = 0; j < 2; ++j) acc[i][j] = (f32x4){0.f, 0.f, 0.f, 0.f};

    // read addressing: byte = row*128 + (slot^(lane&7))*16, slot = ks*4+(lane>>4)
    int slot0 = ((lane >> 4) ^ (lane & 7)) << 4;
    const char* aptr = lds + (wm * 64 + (lane & 15)) * 128 + slot0;
    const char* bptr = lds + 16384 + (wn * 32 + (lane & 15)) * 128 + slot0;

    int NI = K >> 6;
    for (int kt = 0; kt < NI; ++kt) {
        const f16* a = Abase + kt * 64;
        const f16* b = Bbase + kt * 64;
#pragma unroll
        for (int c = 0; c < 4; ++c)
            __builtin_amdgcn_global_load_lds(
                (const __attribute__((address_space(1))) unsigned int*)(a + (long)c * 32 * K),
                (__attribute__((address_space(3))) unsigned int*)(lds + c * 4096 + dstOff), 16, 0, 0);
#pragma unroll
        for (int c = 0; c < 2; ++c)
            __builtin_amdgcn_global_load_lds(
                (const __attribute__((address_space(1))) unsigned int*)(b + (long)c * 32 * K),
                (__attribute__((address_space(3))) unsigned int*)(lds + 16384 + c * 4096 + dstOff), 16, 0, 0);
        __syncthreads();

#pragma unroll
        for (int ks = 0; ks < 2; ++ks) {
            int xo = ((slot0 ^ (ks * 64)) - slot0);
            f16x8 af[4], bf[2];
#pragma unroll
            for (int mi = 0; mi < 4; ++mi)
                af[mi] = *(const f16x8*)(aptr + mi * 2048 + xo);
#pragma unroll
            for (int nj = 0; nj < 2; ++nj)
                bf[nj] = *(const f16x8*)(bptr + nj * 2048 + xo);
#pragma unroll
            for (int mi = 0; mi < 4; ++mi)
#pragma unroll
                for (int nj = 0; nj < 2; ++nj)
                    acc[mi][nj] = __builtin_amdgcn_mfma_f32_16x16x32_f16(af[mi], bf[nj], acc[mi][nj], 0, 0, 0);
        }
        __syncthreads();
    }

    // epilogue
    int cq = lane >> 4, cr = lane & 15;
#pragma unroll
    for (int mi = 0; mi < 4; ++mi) {
#pragma unroll
        for (int nj = 0; nj < 2; ++nj) {
#pragma unroll
            for (int reg = 0; reg < 4; ++reg) {
                int rl = wm * 64 + mi * 16 + cq * 4 + reg;
                if (rl >= mrows) continue;
                int gcol = n0 + wn * 32 + nj * 16 + cr;
                if (gcol >= N) continue;
                float v = acc[mi][nj][reg] + bt[gcol];
                int grow = row0 + rl;
                if (EPI == 0) {
                    outF16[(long)grow * H_ + gcol] = (f16)(v > 0.f ? v : 0.f);
                } else if (EPI == 1) {
                    int r = perm[grow];
                    if (gcol < L_) o0[(long)r * L_ + gcol] = v;
                    else o1[(long)r * L_ + (gcol - L_)] = v;
                } else {
                    o0[(long)perm[grow] * D_ + gcol] = 1.f / (1.f + __expf(-v));
                }
            }
        }
    }
}

extern "C" void kernel_launch(void* const* d_in, const int* in_sizes, int n_in,
                              void* d_out, int out_size, void* d_ws, size_t ws_size,
                              hipStream_t stream) {
    const float* x   = (const float*)d_in[0];
    const float* eps = (const float*)d_in[1];
    const float* eW1 = (const float*)d_in[2];
    const float* eb1 = (const float*)d_in[3];
    const float* eW2 = (const float*)d_in[4];
    const float* eb2 = (const float*)d_in[5];
    const float* eW3 = (const float*)d_in[6];
    const float* eb3 = (const float*)d_in[7];
    const float* dW1 = (const float*)d_in[8];
    const float* db1 = (const float*)d_in[9];
    const float* dW2 = (const float*)d_in[10];
    const float* db2 = (const float*)d_in[11];
    const float* hW  = (const float*)d_in[12];
    const float* hb  = (const float*)d_in[13];
    const int* task  = (const int*)d_in[14];

    float* out = (float*)d_out;
    float* recon = out;
    float* mu = out + (size_t)B_ * D_;
    float* ls = mu + (size_t)B_ * L_;

    char* w = (char*)d_ws;
    size_t o = 0;
    auto alloc = [&](size_t bytes) -> char* {
        char* p = w + o;
        o = (o + bytes + 255) & ~(size_t)255;
        return p;
    };
    int* ctrl  = (int*)alloc(4096);
    int* perm  = (int*)alloc((size_t)B_ * 4);
    f16* Xp    = (f16*)alloc((size_t)(B_ + PADROWS) * KP1 * 2);
    f16* H1    = (f16*)alloc((size_t)(B_ + PADROWS) * H_ * 2);
    f16* H2    = (f16*)alloc((size_t)(B_ + PADROWS) * H_ * 2);
    f16* Z     = (f16*)alloc((size_t)(B_ + PADROWS) * L_ * 2);
    f16* Wt1   = (f16*)alloc((size_t)T_ * H_ * KP1 * 2);
    f16* Wt2   = (f16*)alloc((size_t)T_ * H_ * H_ * 2);
    f16* Wt3   = (f16*)alloc((size_t)T_ * 256 * H_ * 2);
    f16* WtD1  = (f16*)alloc((size_t)H_ * L_ * 2);
    f16* WtD2  = (f16*)alloc((size_t)H_ * H_ * 2);
    f16* WtH   = (f16*)alloc((size_t)T_ * NPH * H_ * 2);
    if (o > ws_size) return;

    k_init<<<1, 64, 0, stream>>>(ctrl);
    k_count<<<B_ / 256, 256, 0, stream>>>(task, ctrl);
    k_scan<<<1, 1, 0, stream>>>(ctrl);
    k_scatter<<<B_ / 256, 256, 0, stream>>>(task, ctrl, perm);
    k_gather_x<<<B_, 256, 0, stream>>>(x, perm, Xp);

    ConvArgs ca;
    int base = 0;
    auto seg = [&](const float* s, f16* d, int K, int N, int Kp, int Np, int T) {
        ConvSeg sg; sg.src = s; sg.dst = d; sg.K = K; sg.N = N; sg.Kp = Kp; sg.Np = Np;
        sg.ntx = Kp / 64; sg.nty = Np / 128; sg.base = base;
        base += sg.ntx * sg.nty * T;
        return sg;
    };
    ca.s[0] = seg(eW1, Wt1, D_, H_, KP1, H_, T_);
    ca.s[1] = seg(eW2, Wt2, H_, H_, H_, H_, T_);
    ca.s[2] = seg(eW3, Wt3, H_, 256, H_, 256, T_);
    ca.s[3] = seg(dW1, WtD1, L_, H_, L_, H_, 1);
    ca.s[4] = seg(dW2, WtD2, H_, H_, H_, H_, 1);
    ca.s[5] = seg(hW, WtH, H_, D_, H_, NPH, T_);
    k_convAll<<<base, 256, 0, stream>>>(ca);

    int gridG = MAXTILES * 16;     // 1184 (grouped, 16 N-tiles of 64)
    int gridG3 = MAXTILES * 4;     // 296 (enc3, N=256 -> 4 N-tiles)
    int gridD = (B_ / 128) * 16;   // 1024 (dense)
    int gridH = MAXTILES * 14;     // 1036 (head, 14 N-tiles cover 784..896)

    // encoder layer 1: Xp(K=896) @ Wt1 -> relu -> H1
    k_gemmD<0, true><<<gridG, 256, 0, stream>>>(
        Xp, Wt1, (long)H_ * KP1, eb1, H_, KP1, H_, 16, H1, nullptr, nullptr, ctrl, perm);
    // encoder layer 2: H1 @ Wt2 -> relu -> H2
    k_gemmD<0, true><<<gridG, 256, 0, stream>>>(
        H1, Wt2, (long)H_ * H_, eb2, H_, H_, H_, 16, H2, nullptr, nullptr, ctrl, perm);
    // encoder layer 3: H2 @ Wt3 -> mu/ls perm-scatter
    k_gemmD<1, true><<<gridG3, 256, 0, stream>>>(
        H2, Wt3, (long)256 * H_, eb3, 256, H_, 256, 4, nullptr, mu, ls, ctrl, perm);
    // z = mu + exp(ls)*eps
    k_z<<<(B_ * L_) / 256, 256, 0, stream>>>(mu, ls, eps, perm, Z);
    // decoder layer 1: Z(K=128) @ WtD1 -> relu -> H1
    k_gemmD<0, false><<<gridD, 256, 0, stream>>>(
        Z, WtD1, 0, db1, 0, L_, H_, 16, H1, nullptr, nullptr, ctrl, perm);
    // decoder layer 2: H1 @ WtD2 -> relu -> H2
    k_gemmD<0, false><<<gridD, 256, 0, stream>>>(
        H1, WtD2, 0, db2, 0, H_, H_, 16, H2, nullptr, nullptr, ctrl, perm);
    // head: H2 @ WtH -> sigmoid -> recon (perm-scatter fp32)
    k_gemmD<2, true><<<gridH, 256, 0, stream>>>(
        H2, WtH, (long)NPH * H_, hb, D_, H_, D_, 14, nullptr, recon, nullptr, ctrl, perm);
}